// Round 3
// baseline (72.942 us; speedup 1.0000x reference)
//
#include <hip/hip_runtime.h>
#include <cfloat>

// Problem constants: N=2048 rows, D=1024, K=256 centroids, NG=512 groups.
#define NROWS 2048
#define DDIM  1024
#define KCEN  256
#define ROWS_PER_BLOCK 4   // one wave (64 lanes) per row, 4 waves = 256 threads

// Single kernel: 512 blocks x 256 threads. Wave w of block b owns row b*4+w.
// Each lane holds 4 float4 chunks (16 scalars) of its row; the row norm is a
// pure wave-shuffle butterfly (no barrier). Only 2 barriers: codebook staging.
__global__ __launch_bounds__(256)
void planar_quant_kernel(const float* __restrict__ x,
                         const float* __restrict__ cen,
                         const float* __restrict__ rot,
                         float* __restrict__ out_xhat,
                         float* __restrict__ out_idx)
{
    __shared__ float s_cen[KCEN];
    __shared__ float s_mid[KCEN];   // s_mid[255] = +inf pad

    const int t    = threadIdx.x;
    const int wave = t >> 6;
    const int lane = t & 63;
    const int row  = blockIdx.x * ROWS_PER_BLOCK + wave;
    const size_t base = (size_t)row * DDIM;

    // Issue all global loads first (vmem in flight across the staging barriers).
    float4 xv[4], rv[4];
    #pragma unroll
    for (int k = 0; k < 4; ++k) {
        const int c = lane + 64 * k;            // float4 index within the row
        xv[k] = *(const float4*)(x + base + 4 * c);
        rv[k] = *(const float4*)(rot + 4 * c);  // (c0,s0,c1,s1) for groups 2c,2c+1
    }

    // Stage sorted centroids + decision midpoints.
    s_cen[t] = cen[t];
    __syncthreads();
    s_mid[t] = (t < KCEN - 1) ? 0.5f * (s_cen[t] + s_cen[t + 1]) : FLT_MAX;

    // Row norm: wave-local butterfly; every lane ends with the full sum.
    float ss = 0.0f;
    #pragma unroll
    for (int k = 0; k < 4; ++k)
        ss += xv[k].x * xv[k].x + xv[k].y * xv[k].y
            + xv[k].z * xv[k].z + xv[k].w * xv[k].w;
    #pragma unroll
    for (int off = 32; off >= 1; off >>= 1)
        ss += __shfl_xor(ss, off, 64);
    const float nrm = fmaxf(sqrtf(ss), 1e-8f);
    const float inv = 1.0f / nrm;

    __syncthreads();   // s_mid visible to all waves

    #pragma unroll
    for (int k = 0; k < 4; ++k) {
        const int c = lane + 64 * k;
        const float4 xc = xv[k];
        const float4 rc = rv[k];

        // Rotate the two pairs.
        const float v0 = xc.x * inv, v1 = xc.y * inv;
        const float v2 = xc.z * inv, v3 = xc.w * inv;
        float r[4];
        r[0] = rc.x * v0 - rc.y * v1;
        r[1] = rc.y * v0 + rc.x * v1;
        r[2] = rc.z * v2 - rc.w * v3;
        r[3] = rc.w * v2 + rc.z * v3;

        // Per-scalar nearest centroid: lower-bound binary search over midpoints
        // (values cluster near 0 -> probes are mostly lane-broadcasts), then a
        // neighbor fix-up with exact distances (argmin first-index tie rule).
        int   qi[4];
        float qv[4];
        #pragma unroll
        for (int e = 0; e < 4; ++e) {
            const float v = r[e];
            int idx = 0;
            #pragma unroll
            for (int step = 128; step >= 1; step >>= 1)
                if (s_mid[idx + step - 1] < v) idx += step;
            float best = fabsf(v - s_cen[idx]);
            if (idx > 0 && fabsf(v - s_cen[idx - 1]) <= best) {
                idx -= 1;
            } else if (idx < KCEN - 1 && fabsf(v - s_cen[idx + 1]) < best) {
                idx += 1;
            }
            qi[e] = idx;
            qv[e] = s_cen[idx];
        }

        // Inverse rotation + rescale; coalesced float4 stores.
        float4 xh;
        xh.x = ( rc.x * qv[0] + rc.y * qv[1]) * nrm;
        xh.y = (-rc.y * qv[0] + rc.x * qv[1]) * nrm;
        xh.z = ( rc.z * qv[2] + rc.w * qv[3]) * nrm;
        xh.w = (-rc.w * qv[2] + rc.z * qv[3]) * nrm;

        float4 fi;
        fi.x = (float)qi[0]; fi.y = (float)qi[1];
        fi.z = (float)qi[2]; fi.w = (float)qi[3];

        *(float4*)(out_xhat + base + 4 * c) = xh;
        *(float4*)(out_idx  + base + 4 * c) = fi;
    }
}

extern "C" void kernel_launch(void* const* d_in, const int* in_sizes, int n_in,
                              void* d_out, int out_size, void* d_ws, size_t ws_size,
                              hipStream_t stream) {
    const float* x   = (const float*)d_in[0];   // [2048*1024]
    const float* cen = (const float*)d_in[1];   // [256] sorted
    const float* rot = (const float*)d_in[2];   // [1024]
    float* out       = (float*)d_out;           // [2 * 2048*1024]

    planar_quant_kernel<<<NROWS / ROWS_PER_BLOCK, 256, 0, stream>>>(
        x, cen, rot, out, out + (size_t)NROWS * DDIM);
}